// Round 9
// baseline (3175.602 us; speedup 1.0000x reference)
//
#include <hip/hip_runtime.h>
#include <hip/hip_bf16.h>
#include <math.h>

// Problem constants
#define SEQ 4096
#define LL  4097           // sequence + CLS
#define HDIM 32
#define FFD 2048
#define NLAYER 6
#define EPSLN 1e-5f
#define NCHUNK 7           // split-K chunks (6 x 608 keys + 1 x 480)
#define CKB 19             // 32-key blocks per chunk (last chunk: 15)
#define KPAD 4128          // keys 0..4096 padded to 129*32
#define QROWS 4160         // 65 * 64 query rows (pad rows zero)
#define NSEG 8             // part2 segments
#define NBLK 1024          // persistent blocks: 4/CU resident by construction
#define NWAVE 4096         // NBLK * 4

#if __has_builtin(__builtin_amdgcn_exp2f)
#define EXP2 __builtin_amdgcn_exp2f
#else
#define EXP2 exp2f
#endif

#define QSCALE 0.7213475204444817f   // 0.5 * log2(e)

typedef short bf16x8 __attribute__((ext_vector_type(8)));
typedef short bf16x4 __attribute__((ext_vector_type(4)));
typedef float f32x4 __attribute__((ext_vector_type(4)));

__device__ __forceinline__ unsigned short f2b(float f) {   // fp32 -> bf16 RNE
  unsigned int b = __float_as_uint(f);
  b += 0x7FFFu + ((b >> 16) & 1u);
  return (unsigned short)(b >> 16);
}

__device__ __forceinline__ unsigned int pk_bf16(float a, float b) {
  __hip_bfloat162 h = __float22bfloat162_rn(make_float2(a, b));
  return *(unsigned int*)&h;
}

// K=16 bf16 MFMA for QK^T (head dim 4 -> half the matrix-pipe cost of K=32).
__device__ __forceinline__ f32x4 mfma_qk(bf16x4 a, bf16x4 b, f32x4 c) {
#if __has_builtin(__builtin_amdgcn_mfma_f32_16x16x16bf16_1k)
  return __builtin_amdgcn_mfma_f32_16x16x16bf16_1k(a, b, c, 0, 0, 0);
#else
  bf16x8 a8 = {a[0], a[1], a[2], a[3], 0, 0, 0, 0};
  bf16x8 b8 = {b[0], b[1], b[2], b[3], 0, 0, 0, 0};
  return __builtin_amdgcn_mfma_f32_16x16x32_bf16(a8, b8, c, 0, 0, 0);
#endif
}

// Device-wide barrier (monotonic counter; all NBLK blocks resident by
// resource construction: 256 thr, VGPR<=128 -> 16 waves/CU, LDS 17.4KB/block
// -> 4 blocks/CU x 256 CU = 1024). Same pattern r2 validated for correctness.
__device__ __forceinline__ void gsync(unsigned* bar, unsigned& tgt) {
  __syncthreads();
  tgt += NBLK;
  if (threadIdx.x == 0) {
    __threadfence();                 // release
    atomicAdd(bar, 1u);
    while (__hip_atomic_load(bar, __ATOMIC_RELAXED, __HIP_MEMORY_SCOPE_AGENT) <
           tgt)
      __builtin_amdgcn_s_sleep(2);
    __threadfence();                 // acquire
  }
  __syncthreads();
}

// wave-level qkv projection + bf16 stores. y = this thread's (row,ch) value.
__device__ __forceinline__ void qkv_wave(float y, int row, bool ok, int lane,
    const float* __restrict__ qw, const float* __restrict__ qb,
    unsigned short* __restrict__ Qb, unsigned short* __restrict__ KB4,
    unsigned short* __restrict__ VB5) {
  int ch = lane & 31;
  float xv[32];
#pragma unroll
  for (int k = 0; k < 32; ++k) xv[k] = __shfl(y, (lane & 32) + k, 64);
#pragma unroll
  for (int t3 = 0; t3 < 3; ++t3) {
    int cc = t3 * 32 + ch;
    const float4* wr = (const float4*)(qw + (size_t)cc * 32);
    float acc = qb[cc];
#pragma unroll
    for (int k8 = 0; k8 < 8; ++k8) {
      float4 wv = wr[k8];
      acc = fmaf(xv[4 * k8 + 0], wv.x, acc);
      acc = fmaf(xv[4 * k8 + 1], wv.y, acc);
      acc = fmaf(xv[4 * k8 + 2], wv.z, acc);
      acc = fmaf(xv[4 * k8 + 3], wv.w, acc);
    }
    if (ok) {
      int h = ch >> 2;
      if (t3 == 0) {
        Qb[(size_t)row * 32 + ch] = f2b(QSCALE * acc);
      } else if (t3 == 1) {
        KB4[((size_t)h * KPAD + row) * 4 + (ch & 3)] = f2b(acc);
      } else {
        int w = row & 31;
        int pos = ((w & 15) << 1) | (w >> 4);
        VB5[((size_t)h * 5 + (ch & 3)) * KPAD + (row & ~31) + pos] = f2b(acc);
      }
    }
  }
}

__global__ __launch_bounds__(256, 4) void k_mega(
    const float* __restrict__ data, const float* __restrict__ lin_w,
    const float* __restrict__ lin_b, const float* __restrict__ qkv_w,
    const float* __restrict__ qkv_b, const float* __restrict__ out_w,
    const float* __restrict__ out_b, const float* __restrict__ ln1_g,
    const float* __restrict__ ln1_b, const float* __restrict__ ff1_w,
    const float* __restrict__ ff1_b, const float* __restrict__ ff2_w,
    const float* __restrict__ ff2_b, const float* __restrict__ ln2_g,
    const float* __restrict__ ln2_b, const float* __restrict__ cls_w,
    const float* __restrict__ cls_b,
    float* __restrict__ X, unsigned short* __restrict__ Xb,
    unsigned short* __restrict__ Qb, unsigned short* __restrict__ KB4,
    unsigned short* __restrict__ VB5, unsigned short* __restrict__ W1B,
    unsigned short* __restrict__ W2B, float* __restrict__ APf,
    float* __restrict__ LP, float* __restrict__ PART2,
    float* __restrict__ out, unsigned* bar) {
  __shared__ unsigned short FsbS[4][16 * 136];   // wave-private FFN transpose
  const int tid = threadIdx.x;
  const int wave = tid >> 6, lane = tid & 63;
  const int l16 = lane & 15, quad = lane >> 4;
  const int r = lane >> 5, ch = lane & 31;
  const unsigned wgid = blockIdx.x * 4 + wave;
  const int gid = blockIdx.x * 256 + tid;
  unsigned tgt = 0;

  // ===== phase 0: weight cvt + pad zero + embed + layer-0 qkv (disjoint) ====
  {
    const int NW = NLAYER * FFD * 32;
    for (int i = gid; i < NW; i += NBLK * 256) {
      W1B[i] = f2b(ff1_w[i]);
      W2B[i] = f2b(ff2_w[i]);
    }
    for (int i = gid; i < (QROWS - LL) * 32; i += NBLK * 256)
      Qb[(size_t)LL * 32 + i] = 0;                 // query pad rows
    for (int i = gid; i < 8 * (KPAD - LL) * 4; i += NBLK * 256) {
      int hh = i / ((KPAD - LL) * 4);
      int rem = i % ((KPAD - LL) * 4);
      KB4[((size_t)hh * KPAD + LL) * 4 + rem] = 0; // K pad rows
    }
    for (int i = gid; i < 8 * 5 * KPAD; i += NBLK * 256) {
      int col = i % KPAD;
      int dd = (i / KPAD) % 5;
      if (dd == 4) {
        int key = (col & ~31) + ((col & 1) << 4) + ((col & 31) >> 1);
        VB5[i] = (key <= 4096) ? 0x3F80 : 0;       // validity row
      } else if (col > 4096) {
        VB5[i] = 0;                                // pad-key V entries
      }
    }
    for (unsigned it = wgid; it < 2049; it += NWAVE) {
      int row = it * 2 + r;
      bool ok = row < LL;
      float val = 0.f;
      if (ok) {
        if (row == 0) {
          val = -1.0f;
        } else {
          int s = row - 1;
          float ts = data[s * 3 + 0];
          float f0 = data[s * 3 + 1];
          float f1 = data[s * 3 + 2];
          float lin =
              f0 * lin_w[ch * 2 + 0] + f1 * lin_w[ch * 2 + 1] + lin_b[ch];
          lin = fmaxf(lin, 0.0f);
          int tsi = (int)(ts / 100.0f);
          int j = ch >> 1;
          float aj = (float)(2 * j) * (float)(-0.28782313662425575);
          float divj = (float)exp((double)aj);
          float ang = (float)tsi * divj;
          float pe = (ch & 1) ? cosf(ang) : sinf(ang);
          val = lin + pe;
        }
        X[(size_t)row * HDIM + ch] = val;
      }
      qkv_wave(val, row, ok, lane, qkv_w, qkv_b, Qb, KB4, VB5);
    }
  }
  gsync(bar, tgt);

  for (int l = 0; l < NLAYER; ++l) {
    // ===== attn phase: 3640 wave items (64q x head x chunk), <=1 per wave ===
    for (unsigned it = wgid; it < 65 * 8 * NCHUNK; it += NWAVE) {
      int c = it % NCHUNK;
      unsigned rest = it / NCHUNK;
      int h = rest & 7;
      int q0 = (rest >> 3) * 64;
      int kb0 = c * CKB * 32;
      int nkb = (c == NCHUNK - 1) ? 15 : CKB;

      const unsigned short* KBh = KB4 + (size_t)h * KPAD * 4;
      const unsigned short* VBh = VB5 + (size_t)h * 5 * KPAD;
      const bool kl = (quad == (h & 3));
      const bool vl = (l16 < 5);
      const int qcol0 = (h >> 2) * 16 + quad * 4;

      bf16x4 aq[4];
#pragma unroll
      for (int t = 0; t < 4; ++t)
        aq[t] = *(const bf16x4*)&Qb[(size_t)(q0 + t * 16 + l16) * 32 + qcol0];

      const bf16x4 zb4 = {0, 0, 0, 0};
      const bf16x8 zb8 = {0, 0, 0, 0, 0, 0, 0, 0};
      f32x4 acc0[4], acc1[4];
#pragma unroll
      for (int t = 0; t < 4; ++t) {
        acc0[t] = (f32x4){0.f, 0.f, 0.f, 0.f};
        acc1[t] = (f32x4){0.f, 0.f, 0.f, 0.f};
      }

      auto step = [&](int k0, f32x4* acc) {
        bf16x4 bk0 = kl ? *(const bf16x4*)&KBh[(size_t)(k0 + l16) * 4] : zb4;
        bf16x4 bk1 =
            kl ? *(const bf16x4*)&KBh[(size_t)(k0 + 16 + l16) * 4] : zb4;
        bf16x8 bv =
            vl ? *(const bf16x8*)&VBh[(size_t)l16 * KPAD + k0 + quad * 8] : zb8;
        f32x4 z = {0.f, 0.f, 0.f, 0.f};
        unsigned pf[4][4];
#pragma unroll
        for (int t = 0; t < 4; ++t) {
          f32x4 s0 = mfma_qk(bk0, aq[t], z);
          f32x4 s1 = mfma_qk(bk1, aq[t], z);
#pragma unroll
          for (int reg = 0; reg < 4; ++reg)
            pf[t][reg] = pk_bf16(EXP2(s0[reg]), EXP2(s1[reg]));
        }
#pragma unroll
        for (int t = 0; t < 4; ++t) {
          bf16x8 pb = *(const bf16x8*)&pf[t][0];
          acc[t] =
              __builtin_amdgcn_mfma_f32_16x16x32_bf16(bv, pb, acc[t], 0, 0, 0);
        }
      };

      int kb = 0;
      for (; kb + 2 <= nkb; kb += 2) {
        step(kb0 + kb * 32, acc0);
        step(kb0 + (kb + 1) * 32, acc1);
      }
      if (kb < nkb) step(kb0 + kb * 32, acc0);

#pragma unroll
      for (int t = 0; t < 4; ++t) {
        f32x4 a = acc0[t] + acc1[t];
        int q = q0 + t * 16 + l16;
        if (q < LL) {
          if (quad == 0) {
            *(float4*)&APf[(((size_t)c * LL + q) * 8 + h) * 4] =
                make_float4(a[0], a[1], a[2], a[3]);
          } else if (quad == 1) {
            LP[((size_t)c * LL + q) * 8 + h] = a[0];
          }
        }
      }
    }
    gsync(bar, tgt);

    // ===== oproj phase: 2049 row-pair items ================================
    {
      const float* owl = out_w + (size_t)l * 32 * 32;
      const float* obl = out_b + (size_t)l * 32;
      const float* g1 = ln1_g + (size_t)l * 32;
      const float* bl1 = ln1_b + (size_t)l * 32;
      int hh = ch >> 2;
      for (unsigned it = wgid; it < 2049; it += NWAVE) {
        int row = it * 2 + r;
        bool ok = row < LL;
        float L = 0.f, A = 0.f;
        if (ok) {
#pragma unroll
          for (int c = 0; c < NCHUNK; ++c) {
            A += APf[((size_t)c * LL + row) * 32 + ch];
            L += LP[((size_t)c * LL + row) * 8 + hh];
          }
        }
        float os = ok ? A / L : 0.f;
        float acc = 0.f;
        const float4* owr = (const float4*)(owl + (size_t)ch * 32);
#pragma unroll
        for (int k8 = 0; k8 < 8; ++k8) {
          float4 wv = owr[k8];
          acc = fmaf(__shfl(os, (lane & 32) + 4 * k8 + 0, 64), wv.x, acc);
          acc = fmaf(__shfl(os, (lane & 32) + 4 * k8 + 1, 64), wv.y, acc);
          acc = fmaf(__shfl(os, (lane & 32) + 4 * k8 + 2, 64), wv.z, acc);
          acc = fmaf(__shfl(os, (lane & 32) + 4 * k8 + 3, 64), wv.w, acc);
        }
        float val = ok ? (X[(size_t)row * HDIM + ch] + acc + obl[ch]) : 0.f;
        float mean = val;
#pragma unroll
        for (int off = 16; off > 0; off >>= 1)
          mean += __shfl_xor(mean, off, 32);
        mean *= (1.f / 32.f);
        float d2 = val - mean;
        float var = d2 * d2;
#pragma unroll
        for (int off = 16; off > 0; off >>= 1) var += __shfl_xor(var, off, 32);
        var *= (1.f / 32.f);
        float y = d2 / sqrtf(var + EPSLN) * g1[ch] + bl1[ch];
        if (ok) {
          X[(size_t)row * HDIM + ch] = y;
          Xb[(size_t)row * HDIM + ch] = f2b(y);
        }
      }
    }
    gsync(bar, tgt);

    // ===== ffnA phase: 2080 wave items (16 rows x 256 f), <=1 per wave =====
    {
      const unsigned short* w1l = W1B + (size_t)l * FFD * 32;
      const unsigned short* w2l = W2B + (size_t)l * FFD * 32;
      const float* fb1 = ff1_b + (size_t)l * FFD;
      for (unsigned it = wgid; it < 260 * 8; it += NWAVE) {
        int y8 = it & 7;
        int rg = it >> 3;
        unsigned short* Fs = &FsbS[wave][0];
        bf16x8 a1 =
            *(const bf16x8*)&Xb[(size_t)(rg * 16 + l16) * 32 + quad * 8];
        f32x4 acc2[2] = {{0.f, 0.f, 0.f, 0.f}, {0.f, 0.f, 0.f, 0.f}};
#pragma unroll
        for (int sg = 0; sg < 2; ++sg) {
          int f0 = (y8 * 2 + sg) * 128;
          f32x4 c1[8];
#pragma unroll
          for (int t = 0; t < 8; ++t) {
            bf16x8 b = *(const bf16x8*)&w1l[(size_t)(f0 + t * 16 + l16) * 32 +
                                            quad * 8];
            f32x4 z = {0.f, 0.f, 0.f, 0.f};
            c1[t] = __builtin_amdgcn_mfma_f32_16x16x32_bf16(a1, b, z, 0, 0, 0);
          }
#pragma unroll
          for (int t = 0; t < 8; ++t) {
            float bb = fb1[f0 + t * 16 + l16];
#pragma unroll
            for (int reg = 0; reg < 4; ++reg) {
              float v = fmaxf(c1[t][reg] + bb, 0.f);
              Fs[(quad * 4 + reg) * 136 + t * 16 + l16] = f2b(v);
            }
          }
          // wave-private transpose via LDS; in-order per-wave DS -> no barrier
#pragma unroll
          for (int kt = 0; kt < 4; ++kt) {
            bf16x8 a2 =
                *(const bf16x8*)&Fs[(size_t)l16 * 136 + kt * 32 + quad * 8];
#pragma unroll
            for (int u = 0; u < 2; ++u) {
              bf16x8 b = *(const bf16x8*)&w2l[(size_t)(u * 16 + l16) * FFD +
                                              f0 + kt * 32 + quad * 8];
              acc2[u] = __builtin_amdgcn_mfma_f32_16x16x32_bf16(a2, b, acc2[u],
                                                                0, 0, 0);
            }
          }
        }
#pragma unroll
        for (int u = 0; u < 2; ++u)
#pragma unroll
          for (int reg = 0; reg < 4; ++reg) {
            int rrow = rg * 16 + quad * 4 + reg;
            if (rrow < LL)
              PART2[((size_t)y8 * LL + rrow) * HDIM + u * 16 + l16] =
                  acc2[u][reg];
          }
      }
    }
    gsync(bar, tgt);

    // ===== ffnB phase: 2049 row-pair items + next qkv / classifier =========
    {
      const float* fb2 = ff2_b + (size_t)l * 32;
      const float* g2 = ln2_g + (size_t)l * 32;
      const float* bl2 = ln2_b + (size_t)l * 32;
      bool lastl = (l == NLAYER - 1);
      const float* qwn = qkv_w + (size_t)(lastl ? 0 : (l + 1)) * 96 * 32;
      const float* qbn = qkv_b + (size_t)(lastl ? 0 : (l + 1)) * 96;
      for (unsigned it = wgid; it < 2049; it += NWAVE) {
        int row = it * 2 + r;
        bool ok = row < LL;
        float s = 0.f;
        if (ok) {
#pragma unroll
          for (int q = 0; q < NSEG; ++q)
            s += PART2[((size_t)q * LL + row) * HDIM + ch];
        }
        float val = ok ? (X[(size_t)row * HDIM + ch] + s + fb2[ch]) : 0.f;
        float mean = val;
#pragma unroll
        for (int off = 16; off > 0; off >>= 1)
          mean += __shfl_xor(mean, off, 32);
        mean *= (1.f / 32.f);
        float d2 = val - mean;
        float var = d2 * d2;
#pragma unroll
        for (int off = 16; off > 0; off >>= 1) var += __shfl_xor(var, off, 32);
        var *= (1.f / 32.f);
        float y = d2 / sqrtf(var + EPSLN) * g2[ch] + bl2[ch];
        if (ok) X[(size_t)row * HDIM + ch] = y;
        if (lastl) {
          if (it == 0 && r == 0) {   // row 0 = CLS
            float t = y * cls_w[ch];
#pragma unroll
            for (int off = 16; off > 0; off >>= 1) t += __shfl_xor(t, off, 32);
            if (ch == 0) out[0] = 1.f / (1.f + expf(-(t + cls_b[0])));
          }
        } else {
          qkv_wave(y, row, ok, lane, qwn, qbn, Qb, KB4, VB5);
        }
      }
    }
    if (l + 1 < NLAYER) gsync(bar, tgt);
  }
}

extern "C" void kernel_launch(void* const* d_in, const int* in_sizes, int n_in,
                              void* d_out, int out_size, void* d_ws,
                              size_t ws_size, hipStream_t stream) {
  const float* data  = (const float*)d_in[0];
  const float* lin_w = (const float*)d_in[1];
  const float* lin_b = (const float*)d_in[2];
  const float* qkv_w = (const float*)d_in[3];
  const float* qkv_b = (const float*)d_in[4];
  const float* out_w = (const float*)d_in[5];
  const float* out_b = (const float*)d_in[6];
  const float* ln1_g = (const float*)d_in[7];
  const float* ln1_b = (const float*)d_in[8];
  const float* ff1_w = (const float*)d_in[9];
  const float* ff1_b = (const float*)d_in[10];
  const float* ff2_w = (const float*)d_in[11];
  const float* ff2_b = (const float*)d_in[12];
  const float* ln2_g = (const float*)d_in[13];
  const float* ln2_b = (const float*)d_in[14];
  const float* cls_w = (const float*)d_in[15];
  const float* cls_b = (const float*)d_in[16];

  char* wsb = (char*)d_ws;
  unsigned* bar = (unsigned*)wsb;                       // 256 B barrier area
  float* X = (float*)(wsb + 256);                       // LL*32 fp32
  unsigned short* Xb  = (unsigned short*)(X + (size_t)LL * 32);  // QROWS*32
  unsigned short* Qb  = Xb + (size_t)QROWS * 32;
  unsigned short* KB4 = Qb + (size_t)QROWS * 32;        // 8*KPAD*4
  unsigned short* VB5 = KB4 + (size_t)8 * KPAD * 4;     // 8*5*KPAD
  unsigned short* W1B = VB5 + (size_t)8 * 5 * KPAD;     // NL*FFD*32
  unsigned short* W2B = W1B + (size_t)NLAYER * FFD * 32;
  float* APf = (float*)(((size_t)(W2B + (size_t)NLAYER * FFD * 32) + 15) &
                        ~(size_t)15);                   // NCHUNK*LL*32 floats
  float* LP = APf + (size_t)NCHUNK * LL * 32;           // NCHUNK*LL*8 floats
  float* PART2 = APf;   // aliased: AP+LP (7*LL*40) >= PART2 (8*LL*32); AP/LP
                        // dead once oproj phase is barrier-complete

  hipMemsetAsync(bar, 0, 256, stream);
  k_mega<<<NBLK, 256, 0, stream>>>(
      data, lin_w, lin_b, qkv_w, qkv_b, out_w, out_b, ln1_g, ln1_b, ff1_w,
      ff1_b, ff2_w, ff2_b, ln2_g, ln2_b, cls_w, cls_b, X, Xb, Qb, KB4, VB5,
      W1B, W2B, APf, LP, PART2, (float*)d_out, bar);
}

// Round 10
// 1472.546 us; speedup vs baseline: 2.1565x; 2.1565x over previous
//
#include <hip/hip_runtime.h>
#include <hip/hip_bf16.h>
#include <math.h>

// Problem constants
#define SEQ 4096
#define LL  4097           // sequence + CLS
#define HDIM 32
#define FFD 2048
#define NLAYER 6
#define EPSLN 1e-5f
#define NCHUNK 8           // split-K chunks over keys (512 keys each, last 544)
#define KPAD 4128          // keys 0..4096 padded to 129*32
#define QROWS 4352         // 17 blocks * 4 waves * 64 queries
#define XROWS 4160         // LL rounded up for ffn A-fragment reads
#define RT 64              // FFN row tile
#define FS 128             // FFN f-segment width
#define NSEG 8             // part2 segments

#if __has_builtin(__builtin_amdgcn_exp2f)
#define EXP2 __builtin_amdgcn_exp2f
#else
#define EXP2 exp2f
#endif

#define QSCALE 0.7213475204444817f   // 0.5 * log2(e)

typedef short bf16x8 __attribute__((ext_vector_type(8)));
typedef short bf16x4 __attribute__((ext_vector_type(4)));
typedef float f32x4 __attribute__((ext_vector_type(4)));

__device__ __forceinline__ unsigned short f2b(float f) {   // fp32 -> bf16 RNE
  unsigned int b = __float_as_uint(f);
  b += 0x7FFFu + ((b >> 16) & 1u);
  return (unsigned short)(b >> 16);
}

__device__ __forceinline__ unsigned int pk_bf16(float a, float b) {
  __hip_bfloat162 h = __float22bfloat162_rn(make_float2(a, b));
  return *(unsigned int*)&h;
}

// K=16 bf16 MFMA for QK^T (head dim 4 -> half the matrix-pipe cost of K=32).
__device__ __forceinline__ f32x4 mfma_qk(bf16x4 a, bf16x4 b, f32x4 c) {
#if __has_builtin(__builtin_amdgcn_mfma_f32_16x16x16bf16_1k)
  return __builtin_amdgcn_mfma_f32_16x16x16bf16_1k(a, b, c, 0, 0, 0);
#else
  bf16x8 a8 = {a[0], a[1], a[2], a[3], 0, 0, 0, 0};
  bf16x8 b8 = {b[0], b[1], b[2], b[3], 0, 0, 0, 0};
  return __builtin_amdgcn_mfma_f32_16x16x32_bf16(a8, b8, c, 0, 0, 0);
#endif
}

// Last-block fixup handshake (split-K pattern, no global barrier):
// every block: release fence + counter bump; the LAST block per group
// acquire-fences and runs the consumer phase for its rows.
__device__ __forceinline__ bool last_block(unsigned* cnt, int contributors,
                                           int* lastFlag) {
  __syncthreads();                      // all block stores issued
  if (threadIdx.x == 0) {
    __builtin_amdgcn_fence(__ATOMIC_RELEASE, "agent");
    unsigned old = __hip_atomic_fetch_add(cnt, 1u, __ATOMIC_RELAXED,
                                          __HIP_MEMORY_SCOPE_AGENT);
    *lastFlag = (old == (unsigned)(contributors - 1));
  }
  __syncthreads();
  if (!*lastFlag) return false;
  if (threadIdx.x == 0) __builtin_amdgcn_fence(__ATOMIC_ACQUIRE, "agent");
  __syncthreads();
  return true;
}

// wave-level qkv projection + bf16 stores. y = this thread's (row,ch) value.
__device__ __forceinline__ void qkv_wave(float y, int row, bool ok, int lane,
    const float* __restrict__ qw, const float* __restrict__ qb,
    unsigned short* __restrict__ Qb, unsigned short* __restrict__ KB4,
    unsigned short* __restrict__ VB5) {
  int ch = lane & 31;
  float xv[32];
#pragma unroll
  for (int k = 0; k < 32; ++k) xv[k] = __shfl(y, (lane & 32) + k, 64);
#pragma unroll
  for (int t3 = 0; t3 < 3; ++t3) {
    int cc = t3 * 32 + ch;
    const float4* wr = (const float4*)(qw + (size_t)cc * 32);
    float acc = qb[cc];
#pragma unroll
    for (int k8 = 0; k8 < 8; ++k8) {
      float4 wv = wr[k8];
      acc = fmaf(xv[4 * k8 + 0], wv.x, acc);
      acc = fmaf(xv[4 * k8 + 1], wv.y, acc);
      acc = fmaf(xv[4 * k8 + 2], wv.z, acc);
      acc = fmaf(xv[4 * k8 + 3], wv.w, acc);
    }
    if (ok) {
      int h = ch >> 2;
      if (t3 == 0) {
        Qb[(size_t)row * 32 + ch] = f2b(QSCALE * acc);
      } else if (t3 == 1) {
        KB4[((size_t)h * KPAD + row) * 4 + (ch & 3)] = f2b(acc);
      } else {
        int w = row & 31;
        int pos = ((w & 15) << 1) | (w >> 4);
        VB5[((size_t)h * 5 + (ch & 3)) * KPAD + (row & ~31) + pos] = f2b(acc);
      }
    }
  }
}

// ---- init: counters + weight cvt + pad zeroing + embed + layer-0 qkv -------
__global__ __launch_bounds__(256) void k_init(const float* __restrict__ data,
    const float* __restrict__ lin_w, const float* __restrict__ lin_b,
    const float* __restrict__ qkv_w, const float* __restrict__ qkv_b,
    const float* __restrict__ ff1_w, const float* __restrict__ ff2_w,
    float* __restrict__ X, unsigned short* __restrict__ Qb,
    unsigned short* __restrict__ KB4, unsigned short* __restrict__ VB5,
    unsigned short* __restrict__ W1B, unsigned short* __restrict__ W2B,
    unsigned* __restrict__ cnt) {
  int gid = blockIdx.x * 256 + threadIdx.x;
  int gsz = gridDim.x * 256;
  if (gid < 1024) cnt[gid] = 0;                     // fixup counters
  const int NW = NLAYER * FFD * 32;
  for (int i = gid; i < NW; i += gsz) {
    W1B[i] = f2b(ff1_w[i]);
    W2B[i] = f2b(ff2_w[i]);
  }
  for (int i = gid; i < (QROWS - LL) * 32; i += gsz)
    Qb[(size_t)LL * 32 + i] = 0;                    // query pad rows
  for (int i = gid; i < 8 * (KPAD - LL) * 4; i += gsz) {
    int hh = i / ((KPAD - LL) * 4);
    int rem = i % ((KPAD - LL) * 4);
    KB4[((size_t)hh * KPAD + LL) * 4 + rem] = 0;    // K pad rows
  }
  for (int i = gid; i < 8 * 5 * KPAD; i += gsz) {
    int col = i % KPAD;
    int dd = (i / KPAD) % 5;
    if (dd == 4) {
      int key = (col & ~31) + ((col & 1) << 4) + ((col & 31) >> 1);
      VB5[i] = (key <= 4096) ? 0x3F80 : 0;          // validity row
    } else if (col > 4096) {
      VB5[i] = 0;                                   // pad-key V entries
    }
  }
  // embed + layer-0 qkv: wave items, 2 rows each
  int wave = threadIdx.x >> 6, lane = threadIdx.x & 63;
  int r = lane >> 5, ch = lane & 31;
  unsigned wgid = blockIdx.x * 4 + wave;
  for (unsigned it = wgid; it < 2049; it += gridDim.x * 4) {
    int row = it * 2 + r;
    bool ok = row < LL;
    float val = 0.f;
    if (ok) {
      if (row == 0) {
        val = -1.0f;
      } else {
        int s = row - 1;
        float ts = data[s * 3 + 0];
        float f0 = data[s * 3 + 1];
        float f1 = data[s * 3 + 2];
        float lin = f0 * lin_w[ch * 2 + 0] + f1 * lin_w[ch * 2 + 1] + lin_b[ch];
        lin = fmaxf(lin, 0.0f);
        int tsi = (int)(ts / 100.0f);
        int j = ch >> 1;
        float aj = (float)(2 * j) * (float)(-0.28782313662425575);
        float divj = (float)exp((double)aj);
        float ang = (float)tsi * divj;
        float pe = (ch & 1) ? cosf(ang) : sinf(ang);
        val = lin + pe;
      }
      X[(size_t)row * HDIM + ch] = val;
    }
    qkv_wave(val, row, ok, lane, qkv_w, qkv_b, Qb, KB4, VB5);
  }
}

// ---- attention (swapped-operand, no LDS) + last-block oproj fixup ----------
// grid (17, 8, NCHUNK). Body identical to r8. The last of the 64 blocks per
// 256-query group runs oproj+residual+LN1 for those rows (32 passes of the
// unchanged oproj body).
__global__ __launch_bounds__(256, 4) void k_attn(
    const unsigned short* __restrict__ Qb, const unsigned short* __restrict__ KB4,
    const unsigned short* __restrict__ VB5, float* __restrict__ LP,
    float* __restrict__ APf,
    float* __restrict__ X, unsigned short* __restrict__ Xb,
    const float* __restrict__ ow, const float* __restrict__ ob,
    const float* __restrict__ g1, const float* __restrict__ b1ln,
    unsigned* __restrict__ cnt) {
  __shared__ int lastFlag;
  int tid = threadIdx.x;
  int wave = tid >> 6, lane = tid & 63;
  int l16 = lane & 15, quad = lane >> 4;
  int h = blockIdx.y, c = blockIdx.z;
  int qs = blockIdx.x * 4 + wave;
  if (qs < 65) {
    int q0 = qs * 64;
    int kb0 = c * 512;
    int nkb = (c == NCHUNK - 1) ? 17 : 16;

    const unsigned short* KBh = KB4 + (size_t)h * KPAD * 4;
    const unsigned short* VBh = VB5 + (size_t)h * 5 * KPAD;
    const bool kl = (quad == (h & 3));    // carrying quad, K=16 contraction
    const bool vl = (l16 < 5);            // only V rows 0..4 are nonzero
    const int qcol0 = (h >> 2) * 16 + quad * 4;

    bf16x4 aq[4];
#pragma unroll
    for (int t = 0; t < 4; ++t)
      aq[t] = *(const bf16x4*)&Qb[(size_t)(q0 + t * 16 + l16) * 32 + qcol0];

    const bf16x4 zb4 = {0, 0, 0, 0};
    const bf16x8 zb8 = {0, 0, 0, 0, 0, 0, 0, 0};
    f32x4 acc0[4], acc1[4];
#pragma unroll
    for (int t = 0; t < 4; ++t) {
      acc0[t] = (f32x4){0.f, 0.f, 0.f, 0.f};
      acc1[t] = (f32x4){0.f, 0.f, 0.f, 0.f};
    }

    auto step = [&](int k0, f32x4* acc) {
      bf16x4 bk0 = kl ? *(const bf16x4*)&KBh[(size_t)(k0 + l16) * 4] : zb4;
      bf16x4 bk1 = kl ? *(const bf16x4*)&KBh[(size_t)(k0 + 16 + l16) * 4] : zb4;
      bf16x8 bv = vl ? *(const bf16x8*)&VBh[(size_t)l16 * KPAD + k0 + quad * 8]
                     : zb8;
      f32x4 z = {0.f, 0.f, 0.f, 0.f};
      unsigned pf[4][4];
#pragma unroll
      for (int t = 0; t < 4; ++t) {
        f32x4 s0 = mfma_qk(bk0, aq[t], z);
        f32x4 s1 = mfma_qk(bk1, aq[t], z);
#pragma unroll
        for (int reg = 0; reg < 4; ++reg)
          pf[t][reg] = pk_bf16(EXP2(s0[reg]), EXP2(s1[reg]));
      }
#pragma unroll
      for (int t = 0; t < 4; ++t) {
        bf16x8 pb = *(const bf16x8*)&pf[t][0];
        acc[t] =
            __builtin_amdgcn_mfma_f32_16x16x32_bf16(bv, pb, acc[t], 0, 0, 0);
      }
    };

    int kb = 0;
    for (; kb + 2 <= nkb; kb += 2) {
      step(kb0 + kb * 32, acc0);
      step(kb0 + (kb + 1) * 32, acc1);
    }
    if (kb < nkb) step(kb0 + kb * 32, acc0);

#pragma unroll
    for (int t = 0; t < 4; ++t) {
      f32x4 a = acc0[t] + acc1[t];
      int q = q0 + t * 16 + l16;
      if (q < LL) {
        if (quad == 0) {
          *(float4*)&APf[(((size_t)c * LL + q) * 8 + h) * 4] =
              make_float4(a[0], a[1], a[2], a[3]);
        } else if (quad == 1) {
          LP[((size_t)c * LL + q) * 8 + h] = a[0];
        }
      }
    }
  }

  // -------- last-block fixup: oproj + residual + LN1 for this q-group ------
  if (!last_block(cnt + blockIdx.x, 8 * NCHUNK, &lastFlag)) return;

  int rr = lane >> 5, ch = lane & 31;
  int hh = ch >> 2;
  const float4* owr = (const float4*)(ow + (size_t)ch * 32);
#pragma unroll 2
  for (int p = 0; p < 32; ++p) {
    int row = blockIdx.x * 256 + p * 8 + wave * 2 + rr;
    bool ok = row < LL;
    float L = 0.f, A = 0.f;
    if (ok) {
#pragma unroll
      for (int c2 = 0; c2 < NCHUNK; ++c2) {
        A += APf[((size_t)c2 * LL + row) * 32 + ch];
        L += LP[((size_t)c2 * LL + row) * 8 + hh];
      }
    }
    float os = ok ? A / L : 0.f;
    float acc = 0.f;
#pragma unroll
    for (int k8 = 0; k8 < 8; ++k8) {
      float4 wv = owr[k8];
      acc = fmaf(__shfl(os, (lane & 32) + 4 * k8 + 0, 64), wv.x, acc);
      acc = fmaf(__shfl(os, (lane & 32) + 4 * k8 + 1, 64), wv.y, acc);
      acc = fmaf(__shfl(os, (lane & 32) + 4 * k8 + 2, 64), wv.z, acc);
      acc = fmaf(__shfl(os, (lane & 32) + 4 * k8 + 3, 64), wv.w, acc);
    }
    float val = ok ? (X[(size_t)row * HDIM + ch] + acc + ob[ch]) : 0.f;
    float mean = val;
#pragma unroll
    for (int off = 16; off > 0; off >>= 1) mean += __shfl_xor(mean, off, 32);
    mean *= (1.f / 32.f);
    float d2 = val - mean;
    float var = d2 * d2;
#pragma unroll
    for (int off = 16; off > 0; off >>= 1) var += __shfl_xor(var, off, 32);
    var *= (1.f / 32.f);
    float y = d2 / sqrtf(var + EPSLN) * g1[ch] + b1ln[ch];
    if (ok) {
      X[(size_t)row * HDIM + ch] = y;
      Xb[(size_t)row * HDIM + ch] = f2b(y);
    }
  }
}

// ---- FFN (GEMM1+relu+GEMM2, wave-private transpose) + last-block ffnB ------
// grid (65, NSEG). Body identical to r8 k_ffnA. Last of the 8 y-blocks per
// 64-row group runs combine+residual+LN2+next-qkv (8 passes of unchanged
// ffnB body).
__global__ __launch_bounds__(256) void k_ffn(
    const unsigned short* __restrict__ Xb,
    const unsigned short* __restrict__ w1b, const float* __restrict__ b1,
    const unsigned short* __restrict__ w2b, float* __restrict__ part2,
    float* __restrict__ X, const float* __restrict__ b2,
    const float* __restrict__ g2, const float* __restrict__ bln2,
    const float* __restrict__ qw, const float* __restrict__ qb,
    unsigned short* __restrict__ Qb, unsigned short* __restrict__ KB4,
    unsigned short* __restrict__ VB5, int do_qkv,
    const float* __restrict__ cw, const float* __restrict__ cb,
    float* __restrict__ out, unsigned* __restrict__ cnt) {
  __shared__ unsigned short Fsb[RT * 136];
  __shared__ int lastFlag;
  int tid = threadIdx.x;
  int r0 = blockIdx.x * RT;
  int wave = tid >> 6, lane = tid & 63;
  int l16 = lane & 15, quad = lane >> 4;
  int m0 = wave * 16;

  bf16x8 a1 = *(const bf16x8*)&Xb[(size_t)(r0 + m0 + l16) * 32 + quad * 8];
  f32x4 acc[2] = {{0.f, 0.f, 0.f, 0.f}, {0.f, 0.f, 0.f, 0.f}};

#pragma unroll
  for (int sg = 0; sg < 2; ++sg) {
    int f0 = (blockIdx.y * 2 + sg) * FS;
    f32x4 c1[8];
#pragma unroll
    for (int t = 0; t < 8; ++t) {
      bf16x8 b =
          *(const bf16x8*)&w1b[(size_t)(f0 + t * 16 + l16) * 32 + quad * 8];
      f32x4 z = {0.f, 0.f, 0.f, 0.f};
      c1[t] = __builtin_amdgcn_mfma_f32_16x16x32_bf16(a1, b, z, 0, 0, 0);
    }
#pragma unroll
    for (int t = 0; t < 8; ++t) {
      float bb = b1[f0 + t * 16 + l16];
#pragma unroll
      for (int reg = 0; reg < 4; ++reg) {
        float v = fmaxf(c1[t][reg] + bb, 0.f);
        int rrow = m0 + quad * 4 + reg;
        Fsb[rrow * 136 + t * 16 + l16] = f2b(v);
      }
    }
    // Fsb is wave-private; in-order per-wave DS -> no barrier
#pragma unroll
    for (int kt = 0; kt < 4; ++kt) {
      bf16x8 a2 = *(const bf16x8*)&Fsb[(m0 + l16) * 136 + kt * 32 + quad * 8];
#pragma unroll
      for (int u = 0; u < 2; ++u) {
        bf16x8 b = *(const bf16x8*)&w2b[(size_t)(u * 16 + l16) * FFD + f0 +
                                        kt * 32 + quad * 8];
        acc[u] = __builtin_amdgcn_mfma_f32_16x16x32_bf16(a2, b, acc[u], 0, 0, 0);
      }
    }
  }
#pragma unroll
  for (int u = 0; u < 2; ++u) {
#pragma unroll
    for (int reg = 0; reg < 4; ++reg) {
      int rrow = r0 + m0 + quad * 4 + reg;
      if (rrow < LL)
        part2[((size_t)blockIdx.y * LL + rrow) * HDIM + u * 16 + l16] =
            acc[u][reg];
    }
  }

  // -------- last-block fixup: combine + residual + LN2 + qkv/classifier ----
  if (!last_block(cnt + blockIdx.x, NSEG, &lastFlag)) return;

  int rr = lane >> 5, ch = lane & 31;
#pragma unroll 2
  for (int p = 0; p < 8; ++p) {
    int row = r0 + p * 8 + wave * 2 + rr;
    bool ok = row < LL;
    float s = 0.f;
    if (ok) {
#pragma unroll
      for (int q = 0; q < NSEG; ++q)
        s += part2[((size_t)q * LL + row) * HDIM + ch];
    }
    float val = ok ? (X[(size_t)row * HDIM + ch] + s + b2[ch]) : 0.f;
    float mean = val;
#pragma unroll
    for (int off = 16; off > 0; off >>= 1) mean += __shfl_xor(mean, off, 32);
    mean *= (1.f / 32.f);
    float d = val - mean;
    float var = d * d;
#pragma unroll
    for (int off = 16; off > 0; off >>= 1) var += __shfl_xor(var, off, 32);
    var *= (1.f / 32.f);
    float y = d / sqrtf(var + EPSLN) * g2[ch] + bln2[ch];
    if (ok) X[(size_t)row * HDIM + ch] = y;
    if (do_qkv) {
      qkv_wave(y, row, ok, lane, qw, qb, Qb, KB4, VB5);
    } else if (blockIdx.x == 0 && p == 0 && wave == 0 && rr == 0) {
      // row 0 = CLS
      float t = y * cw[ch];
#pragma unroll
      for (int off = 16; off > 0; off >>= 1) t += __shfl_xor(t, off, 32);
      if (ch == 0) out[0] = 1.f / (1.f + expf(-(t + cb[0])));
    }
  }
}

extern "C" void kernel_launch(void* const* d_in, const int* in_sizes, int n_in,
                              void* d_out, int out_size, void* d_ws,
                              size_t ws_size, hipStream_t stream) {
  const float* data  = (const float*)d_in[0];
  const float* lin_w = (const float*)d_in[1];
  const float* lin_b = (const float*)d_in[2];
  const float* qkv_w = (const float*)d_in[3];
  const float* qkv_b = (const float*)d_in[4];
  const float* out_w = (const float*)d_in[5];
  const float* out_b = (const float*)d_in[6];
  const float* ln1_g = (const float*)d_in[7];
  const float* ln1_b = (const float*)d_in[8];
  const float* ff1_w = (const float*)d_in[9];
  const float* ff1_b = (const float*)d_in[10];
  const float* ff2_w = (const float*)d_in[11];
  const float* ff2_b = (const float*)d_in[12];
  const float* ln2_g = (const float*)d_in[13];
  const float* ln2_b = (const float*)d_in[14];
  const float* cls_w = (const float*)d_in[15];
  const float* cls_b = (const float*)d_in[16];

  char* wsb = (char*)d_ws;
  unsigned* cnt = (unsigned*)wsb;                       // 4 KB counters
  float* X = (float*)(wsb + 4096);                      // LL*32 fp32
  unsigned short* Xb  = (unsigned short*)(X + (size_t)LL * 32);
  unsigned short* Qb  = Xb + (size_t)XROWS * 32;
  unsigned short* KB4 = Qb + (size_t)QROWS * 32;        // 8*KPAD*4
  unsigned short* VB5 = KB4 + (size_t)8 * KPAD * 4;     // 8*5*KPAD
  unsigned short* W1B = VB5 + (size_t)8 * 5 * KPAD;     // NL*FFD*32
  unsigned short* W2B = W1B + (size_t)NLAYER * FFD * 32;
  float* APf = (float*)(((size_t)(W2B + (size_t)NLAYER * FFD * 32) + 15) &
                        ~(size_t)15);                   // NCHUNK*LL*32 floats
  float* LP = APf + (size_t)NCHUNK * LL * 32;           // NCHUNK*LL*8 floats
  float* PART2 = APf;   // aliased; AP/LP dead once attn-tail oproj has run

  k_init<<<1024, 256, 0, stream>>>(data, lin_w, lin_b, qkv_w, qkv_b,
                                   ff1_w, ff2_w, X, Qb, KB4, VB5, W1B, W2B,
                                   cnt);
  for (int l = 0; l < NLAYER; ++l) {
    k_attn<<<dim3(17, 8, NCHUNK), 256, 0, stream>>>(
        Qb, KB4, VB5, LP, APf, X, Xb,
        out_w + (size_t)l * 32 * 32, out_b + (size_t)l * 32,
        ln1_g + (size_t)l * 32, ln1_b + (size_t)l * 32,
        cnt + l * 32);
    int nl = l + 1;
    int do_qkv = (nl < NLAYER) ? 1 : 0;
    const float* qw = qkv_w + (size_t)(do_qkv ? nl : 0) * 96 * 32;
    const float* qb = qkv_b + (size_t)(do_qkv ? nl : 0) * 96;
    k_ffn<<<dim3((LL + RT - 1) / RT, NSEG), 256, 0, stream>>>(
        Xb, W1B + (size_t)l * FFD * 32, ff1_b + (size_t)l * FFD,
        W2B + (size_t)l * FFD * 32, PART2,
        X, ff2_b + (size_t)l * 32,
        ln2_g + (size_t)l * 32, ln2_b + (size_t)l * 32,
        qw, qb, Qb, KB4, VB5, do_qkv, cls_w, cls_b, (float*)d_out,
        cnt + 192 + l * 128);
  }
}

// Round 11
// 437.570 us; speedup vs baseline: 7.2574x; 3.3653x over previous
//
#include <hip/hip_runtime.h>
#include <hip/hip_bf16.h>
#include <math.h>

// Problem constants
#define SEQ 4096
#define LL  4097           // sequence + CLS
#define HDIM 32
#define FFD 2048
#define NLAYER 6
#define EPSLN 1e-5f
#define NCHUNK 16          // split-K chunks over keys (256 keys each, last 288)
#define KPAD 4128          // keys 0..4096 padded to 129*32
#define QROWS 4352         // 17 blocks * 4 waves * 64 queries
#define XROWS 4160         // LL rounded up for ffnA A-fragment reads
#define RT 64              // FFN row tile
#define FS 128             // FFN f-segment width
#define NSEG 8             // part2 segments

#if __has_builtin(__builtin_amdgcn_exp2f)
#define EXP2 __builtin_amdgcn_exp2f
#else
#define EXP2 exp2f
#endif

#define QSCALE 0.7213475204444817f   // 0.5 * log2(e)

typedef short bf16x8 __attribute__((ext_vector_type(8)));
typedef short bf16x4 __attribute__((ext_vector_type(4)));
typedef float f32x4 __attribute__((ext_vector_type(4)));

__device__ __forceinline__ unsigned short f2b(float f) {   // fp32 -> bf16 RNE
  unsigned int b = __float_as_uint(f);
  b += 0x7FFFu + ((b >> 16) & 1u);
  return (unsigned short)(b >> 16);
}

__device__ __forceinline__ unsigned int pk_bf16(float a, float b) {
  __hip_bfloat162 h = __float22bfloat162_rn(make_float2(a, b));
  return *(unsigned int*)&h;
}

// K=16 bf16 MFMA for QK^T (head dim 4 -> half the matrix-pipe cost of K=32).
__device__ __forceinline__ f32x4 mfma_qk(bf16x4 a, bf16x4 b, f32x4 c) {
#if __has_builtin(__builtin_amdgcn_mfma_f32_16x16x16bf16_1k)
  return __builtin_amdgcn_mfma_f32_16x16x16bf16_1k(a, b, c, 0, 0, 0);
#else
  bf16x8 a8 = {a[0], a[1], a[2], a[3], 0, 0, 0, 0};
  bf16x8 b8 = {b[0], b[1], b[2], b[3], 0, 0, 0, 0};
  return __builtin_amdgcn_mfma_f32_16x16x32_bf16(a8, b8, c, 0, 0, 0);
#endif
}

// Buffers:
//  Qb  [QROWS][32]  bf16, pre-scaled by QSCALE (pad rows zero). For head h,
//      QK's B-operand slice = columns 16*(h>>2) + quad*4 .. +3 (the carrying
//      quad h&3 reads exactly columns 4h..4h+3).
//  KB4 [8][KPAD][4] bf16 — head h's 4 K dims per key; pad rows zeroed once.
//  VB5 [8][5][KPAD] bf16, rows 0..3 = V dims (permuted key order), row 4 =
//      validity. Key permutation within 32-blocks: pos = ((w&15)<<1) | (w>>4)
//      — so pk(exp(S[k]), exp(S[k+16])) is directly the PV B-frag in-lane.
//  AP [(c*LL+q)*32 + h*4+d] float — split-K numerator partials; a row's 32
//      lanes read ONE contiguous 128B line per chunk.
//  LP [(c*LL+q)*8 + h] float — split-K denominators, one 32B segment/row.
//  Xb [XROWS][32] bf16 — post-LN1 X, ffnA's GEMM1 A operand.

// wave-level qkv projection + bf16 stores. y = this thread's (row,ch) value.
__device__ __forceinline__ void qkv_wave(float y, int row, bool ok, int lane,
    const float* __restrict__ qw, const float* __restrict__ qb,
    unsigned short* __restrict__ Qb, unsigned short* __restrict__ KB4,
    unsigned short* __restrict__ VB5) {
  int ch = lane & 31;
  float xv[32];
#pragma unroll
  for (int k = 0; k < 32; ++k) xv[k] = __shfl(y, (lane & 32) + k, 64);
#pragma unroll
  for (int t3 = 0; t3 < 3; ++t3) {
    int cc = t3 * 32 + ch;
    const float4* wr = (const float4*)(qw + (size_t)cc * 32);
    float acc = qb[cc];
#pragma unroll
    for (int k8 = 0; k8 < 8; ++k8) {
      float4 wv = wr[k8];
      acc = fmaf(xv[4 * k8 + 0], wv.x, acc);
      acc = fmaf(xv[4 * k8 + 1], wv.y, acc);
      acc = fmaf(xv[4 * k8 + 2], wv.z, acc);
      acc = fmaf(xv[4 * k8 + 3], wv.w, acc);
    }
    if (ok) {
      int h = ch >> 2;
      if (t3 == 0) {
        Qb[(size_t)row * 32 + ch] = f2b(QSCALE * acc);
      } else if (t3 == 1) {
        KB4[((size_t)h * KPAD + row) * 4 + (ch & 3)] = f2b(acc);
      } else {
        int w = row & 31;
        int pos = ((w & 15) << 1) | (w >> 4);
        VB5[((size_t)h * 5 + (ch & 3)) * KPAD + (row & ~31) + pos] = f2b(acc);
      }
    }
  }
}

// ---- init: weight cvt + pad zeroing + embed + layer-0 qkv (all disjoint) ---
__global__ __launch_bounds__(256) void k_init(const float* __restrict__ data,
    const float* __restrict__ lin_w, const float* __restrict__ lin_b,
    const float* __restrict__ qkv_w, const float* __restrict__ qkv_b,
    const float* __restrict__ ff1_w, const float* __restrict__ ff2_w,
    float* __restrict__ X, unsigned short* __restrict__ Qb,
    unsigned short* __restrict__ KB4, unsigned short* __restrict__ VB5,
    unsigned short* __restrict__ W1B, unsigned short* __restrict__ W2B) {
  int gid = blockIdx.x * 256 + threadIdx.x;
  int gsz = gridDim.x * 256;
  const int NW = NLAYER * FFD * 32;
  for (int i = gid; i < NW; i += gsz) {
    W1B[i] = f2b(ff1_w[i]);
    W2B[i] = f2b(ff2_w[i]);
  }
  for (int i = gid; i < (QROWS - LL) * 32; i += gsz)
    Qb[(size_t)LL * 32 + i] = 0;                    // query pad rows
  for (int i = gid; i < 8 * (KPAD - LL) * 4; i += gsz) {
    int hh = i / ((KPAD - LL) * 4);
    int rem = i % ((KPAD - LL) * 4);
    KB4[((size_t)hh * KPAD + LL) * 4 + rem] = 0;    // K pad rows
  }
  for (int i = gid; i < 8 * 5 * KPAD; i += gsz) {
    int col = i % KPAD;
    int dd = (i / KPAD) % 5;
    if (dd == 4) {
      int key = (col & ~31) + ((col & 1) << 4) + ((col & 31) >> 1);
      VB5[i] = (key <= 4096) ? 0x3F80 : 0;          // validity row
    } else if (col > 4096) {
      VB5[i] = 0;                                   // pad-key V entries
    }
  }
  // embed + layer-0 qkv: wave items, 2 rows each
  int wave = threadIdx.x >> 6, lane = threadIdx.x & 63;
  int r = lane >> 5, ch = lane & 31;
  unsigned wgid = blockIdx.x * 4 + wave;
  for (unsigned it = wgid; it < 2049; it += gridDim.x * 4) {
    int row = it * 2 + r;
    bool ok = row < LL;
    float val = 0.f;
    if (ok) {
      if (row == 0) {
        val = -1.0f;
      } else {
        int s = row - 1;
        float ts = data[s * 3 + 0];
        float f0 = data[s * 3 + 1];
        float f1 = data[s * 3 + 2];
        float lin = f0 * lin_w[ch * 2 + 0] + f1 * lin_w[ch * 2 + 1] + lin_b[ch];
        lin = fmaxf(lin, 0.0f);
        int tsi = (int)(ts / 100.0f);
        int j = ch >> 1;
        float aj = (float)(2 * j) * (float)(-0.28782313662425575);
        float divj = (float)exp((double)aj);
        float ang = (float)tsi * divj;
        float pe = (ch & 1) ? cosf(ang) : sinf(ang);
        val = lin + pe;
      }
      X[(size_t)row * HDIM + ch] = val;
    }
    qkv_wave(val, row, ok, lane, qkv_w, qkv_b, Qb, KB4, VB5);
  }
}

// ---- attention, swapped-operand MFMA: NO LDS, no transpose -----------------
// QK via 16x16x16 (K=16): mfma(K, Q) gives S^T: lane = q-col (l16), regs =
// keys quad*4+reg (+16 in s1). pk(exp(s0[r]), exp(s1[r])) lands keys exactly
// in VB5's permuted order at contraction positions quad*8+{2r,2r+1} -> the
// packed dwords ARE the PV B-fragment in-lane. grid (17, 8, NCHUNK=16):
// 2176 blocks ~ 8.5/CU for max TLP (VGPR 64 -> 8 blocks/CU resident).
__global__ __launch_bounds__(256, 4) void k_attn(
    const unsigned short* __restrict__ Qb, const unsigned short* __restrict__ KB4,
    const unsigned short* __restrict__ VB5, float* __restrict__ LP,
    float4* __restrict__ AP4) {
  int tid = threadIdx.x;
  int wave = tid >> 6, lane = tid & 63;
  int l16 = lane & 15, quad = lane >> 4;
  int h = blockIdx.y, c = blockIdx.z;
  int qs = blockIdx.x * 4 + wave;
  if (qs >= 65) return;                  // wave-uniform exit, no barriers used
  int q0 = qs * 64;
  int kb0 = c * 256;
  int nkb = (c == NCHUNK - 1) ? 9 : 8;

  const unsigned short* KBh = KB4 + (size_t)h * KPAD * 4;
  const unsigned short* VBh = VB5 + (size_t)h * 5 * KPAD;
  const bool kl = (quad == (h & 3));    // carrying quad for K=16 contraction
  const bool vl = (l16 < 5);            // only V rows 0..4 are nonzero
  const int qcol0 = (h >> 2) * 16 + quad * 4;   // Q columns for this quad

  bf16x4 aq[4];                          // Q tiles: B-operand (row = l16 = q)
#pragma unroll
  for (int t = 0; t < 4; ++t)
    aq[t] = *(const bf16x4*)&Qb[(size_t)(q0 + t * 16 + l16) * 32 + qcol0];

  const bf16x4 zb4 = {0, 0, 0, 0};
  const bf16x8 zb8 = {0, 0, 0, 0, 0, 0, 0, 0};
  f32x4 acc0[4], acc1[4];
#pragma unroll
  for (int t = 0; t < 4; ++t) {
    acc0[t] = (f32x4){0.f, 0.f, 0.f, 0.f};
    acc1[t] = (f32x4){0.f, 0.f, 0.f, 0.f};
  }

  auto step = [&](int k0, f32x4* acc) {
    bf16x4 bk0 = kl ? *(const bf16x4*)&KBh[(size_t)(k0 + l16) * 4] : zb4;
    bf16x4 bk1 = kl ? *(const bf16x4*)&KBh[(size_t)(k0 + 16 + l16) * 4] : zb4;
    bf16x8 bv = vl ? *(const bf16x8*)&VBh[(size_t)l16 * KPAD + k0 + quad * 8]
                   : zb8;
    f32x4 z = {0.f, 0.f, 0.f, 0.f};
    unsigned pf[4][4];                   // packed P fragments (bf16x8 each)
#pragma unroll
    for (int t = 0; t < 4; ++t) {
      f32x4 s0 = mfma_qk(bk0, aq[t], z);
      f32x4 s1 = mfma_qk(bk1, aq[t], z);
#pragma unroll
      for (int reg = 0; reg < 4; ++reg)
        pf[t][reg] = pk_bf16(EXP2(s0[reg]), EXP2(s1[reg]));
    }
#pragma unroll
    for (int t = 0; t < 4; ++t) {
      bf16x8 pb = *(const bf16x8*)&pf[t][0];
      acc[t] = __builtin_amdgcn_mfma_f32_16x16x32_bf16(bv, pb, acc[t], 0, 0, 0);
    }
  };

  int kb = 0;
  for (; kb + 2 <= nkb; kb += 2) {
    step(kb0 + kb * 32, acc0);
    step(kb0 + (kb + 1) * 32, acc1);
  }
  if (kb < nkb) step(kb0 + kb * 32, acc0);

  // Output: lane holds O^T rows d=quad*4+reg for q=l16 of each tile.
  // quad0: d0..3 -> float4 at [q][h]; quad1 reg0: d4 = L (validity sum).
#pragma unroll
  for (int t = 0; t < 4; ++t) {
    f32x4 a = acc0[t] + acc1[t];
    int q = q0 + t * 16 + l16;
    if (q < LL) {
      if (quad == 0) {
        AP4[((size_t)c * LL + q) * 8 + h] = make_float4(a[0], a[1], a[2], a[3]);
      } else if (quad == 1) {
        LP[((size_t)c * LL + q) * 8 + h] = a[0];
      }
    }
  }
}

// ------- fused: sum split-K partials + o-proj + residual + LN1 --------------
// Coalesced partial loads: per (row, chunk) the 32 lanes read one 128B AP
// line + one 32B LP segment. No LDS, no syncthreads (in-wave shfl bcast).
__global__ __launch_bounds__(256) void k_oproj(const float* __restrict__ LP,
    const float* __restrict__ APf, float* __restrict__ x,
    unsigned short* __restrict__ Xb,
    const float* __restrict__ ow, const float* __restrict__ ob,
    const float* __restrict__ g, const float* __restrict__ bln) {
  int tid = threadIdx.x;
  int wave = tid >> 6, lane = tid & 63;
  int r = lane >> 5, ch = lane & 31;
  int row = blockIdx.x * 8 + wave * 2 + r;
  bool ok = row < LL;
  int hh = ch >> 2;
  float L = 0.f, A = 0.f;
  if (ok) {
#pragma unroll
    for (int c = 0; c < NCHUNK; ++c) {
      A += APf[((size_t)c * LL + row) * 32 + ch];
      L += LP[((size_t)c * LL + row) * 8 + hh];
    }
  }
  float os = ok ? A / L : 0.f;
  float acc = 0.f;
  const float4* owr = (const float4*)(ow + (size_t)ch * 32);
#pragma unroll
  for (int k8 = 0; k8 < 8; ++k8) {
    float4 wv = owr[k8];
    acc = fmaf(__shfl(os, (lane & 32) + 4 * k8 + 0, 64), wv.x, acc);
    acc = fmaf(__shfl(os, (lane & 32) + 4 * k8 + 1, 64), wv.y, acc);
    acc = fmaf(__shfl(os, (lane & 32) + 4 * k8 + 2, 64), wv.z, acc);
    acc = fmaf(__shfl(os, (lane & 32) + 4 * k8 + 3, 64), wv.w, acc);
  }
  float val = ok ? (x[(size_t)row * HDIM + ch] + acc + ob[ch]) : 0.f;
  float mean = val;
#pragma unroll
  for (int off = 16; off > 0; off >>= 1) mean += __shfl_xor(mean, off, 32);
  mean *= (1.f / 32.f);
  float d2 = val - mean;
  float var = d2 * d2;
#pragma unroll
  for (int off = 16; off > 0; off >>= 1) var += __shfl_xor(var, off, 32);
  var *= (1.f / 32.f);
  float y = d2 / sqrtf(var + EPSLN) * g[ch] + bln[ch];
  if (ok) {
    x[(size_t)row * HDIM + ch] = y;
    Xb[(size_t)row * HDIM + ch] = f2b(y);
  }
}

// ---------------- FFN part A via MFMA bf16, 2 f-segments per block ----------
// Fsb is wave-private (wave w writes rows m0..m0+15, reads rows m0+l16):
// in-order per-wave DS ops -> NO barriers needed at all.
__global__ __launch_bounds__(256) void k_ffnA(
    const unsigned short* __restrict__ Xb,
    const unsigned short* __restrict__ w1b, const float* __restrict__ b1,
    const unsigned short* __restrict__ w2b, float* __restrict__ part2) {
  __shared__ unsigned short Fsb[RT * 136];
  int tid = threadIdx.x;
  int r0 = blockIdx.x * RT;
  int wave = tid >> 6, lane = tid & 63;
  int l16 = lane & 15, quad = lane >> 4;
  int m0 = wave * 16;

  bf16x8 a1 = *(const bf16x8*)&Xb[(size_t)(r0 + m0 + l16) * 32 + quad * 8];
  f32x4 acc[2] = {{0.f, 0.f, 0.f, 0.f}, {0.f, 0.f, 0.f, 0.f}};

#pragma unroll
  for (int sg = 0; sg < 2; ++sg) {
    int f0 = (blockIdx.y * 2 + sg) * FS;
    f32x4 c1[8];
#pragma unroll
    for (int t = 0; t < 8; ++t) {
      bf16x8 b =
          *(const bf16x8*)&w1b[(size_t)(f0 + t * 16 + l16) * 32 + quad * 8];
      f32x4 z = {0.f, 0.f, 0.f, 0.f};
      c1[t] = __builtin_amdgcn_mfma_f32_16x16x32_bf16(a1, b, z, 0, 0, 0);
    }
#pragma unroll
    for (int t = 0; t < 8; ++t) {
      float bb = b1[f0 + t * 16 + l16];
#pragma unroll
      for (int reg = 0; reg < 4; ++reg) {
        float v = fmaxf(c1[t][reg] + bb, 0.f);
        int rrow = m0 + quad * 4 + reg;
        Fsb[rrow * 136 + t * 16 + l16] = f2b(v);
      }
    }
#pragma unroll
    for (int kt = 0; kt < 4; ++kt) {
      bf16x8 a2 = *(const bf16x8*)&Fsb[(m0 + l16) * 136 + kt * 32 + quad * 8];
#pragma unroll
      for (int u = 0; u < 2; ++u) {
        bf16x8 b = *(const bf16x8*)&w2b[(size_t)(u * 16 + l16) * FFD + f0 +
                                        kt * 32 + quad * 8];
        acc[u] = __builtin_amdgcn_mfma_f32_16x16x32_bf16(a2, b, acc[u], 0, 0, 0);
      }
    }
  }
#pragma unroll
  for (int u = 0; u < 2; ++u) {
#pragma unroll
    for (int reg = 0; reg < 4; ++reg) {
      int rrow = r0 + m0 + quad * 4 + reg;
      if (rrow < LL)
        part2[((size_t)blockIdx.y * LL + rrow) * HDIM + u * 16 + l16] =
            acc[u][reg];
    }
  }
}

// ------ FFN part B: combine + residual + LN2 + next qkv (bf16) + final ------
__global__ __launch_bounds__(256) void k_ffnB_qkv(float* __restrict__ x,
    const float* __restrict__ part2, const float* __restrict__ b2,
    const float* __restrict__ g, const float* __restrict__ bln,
    const float* __restrict__ qw, const float* __restrict__ qb,
    unsigned short* __restrict__ Qb, unsigned short* __restrict__ KB4,
    unsigned short* __restrict__ VB5, int do_qkv,
    const float* __restrict__ cw, const float* __restrict__ cb,
    float* __restrict__ out) {
  int tid = threadIdx.x;
  int wave = tid >> 6, lane = tid & 63;
  int r = lane >> 5, ch = lane & 31;
  int row = blockIdx.x * 8 + wave * 2 + r;
  bool ok = row < LL;
  float s = 0.f;
  if (ok) {
#pragma unroll
    for (int q = 0; q < NSEG; ++q)
      s += part2[((size_t)q * LL + row) * HDIM + ch];
  }
  float val = ok ? (x[(size_t)row * HDIM + ch] + s + b2[ch]) : 0.f;
  float mean = val;
#pragma unroll
  for (int off = 16; off > 0; off >>= 1) mean += __shfl_xor(mean, off, 32);
  mean *= (1.f / 32.f);
  float d = val - mean;
  float var = d * d;
#pragma unroll
  for (int off = 16; off > 0; off >>= 1) var += __shfl_xor(var, off, 32);
  var *= (1.f / 32.f);
  float y = d / sqrtf(var + EPSLN) * g[ch] + bln[ch];
  if (ok) x[(size_t)row * HDIM + ch] = y;
  if (!do_qkv) {
    if (blockIdx.x == 0 && wave == 0 && r == 0) {
      float t = y * cw[ch];
#pragma unroll
      for (int off = 16; off > 0; off >>= 1) t += __shfl_xor(t, off, 32);
      if (ch == 0) {
        float z = t + cb[0];
        out[0] = 1.f / (1.f + expf(-z));
      }
    }
    return;
  }
  qkv_wave(y, row, ok, lane, qw, qb, Qb, KB4, VB5);
}

extern "C" void kernel_launch(void* const* d_in, const int* in_sizes, int n_in,
                              void* d_out, int out_size, void* d_ws,
                              size_t ws_size, hipStream_t stream) {
  const float* data  = (const float*)d_in[0];
  const float* lin_w = (const float*)d_in[1];
  const float* lin_b = (const float*)d_in[2];
  const float* qkv_w = (const float*)d_in[3];
  const float* qkv_b = (const float*)d_in[4];
  const float* out_w = (const float*)d_in[5];
  const float* out_b = (const float*)d_in[6];
  const float* ln1_g = (const float*)d_in[7];
  const float* ln1_b = (const float*)d_in[8];
  const float* ff1_w = (const float*)d_in[9];
  const float* ff1_b = (const float*)d_in[10];
  const float* ff2_w = (const float*)d_in[11];
  const float* ff2_b = (const float*)d_in[12];
  const float* ln2_g = (const float*)d_in[13];
  const float* ln2_b = (const float*)d_in[14];
  const float* cls_w = (const float*)d_in[15];
  const float* cls_b = (const float*)d_in[16];

  char* wsb = (char*)d_ws;
  float* X = (float*)wsb;                               // LL*32 fp32
  unsigned short* Xb  = (unsigned short*)(X + (size_t)LL * 32);
  unsigned short* Qb  = Xb + (size_t)XROWS * 32;
  unsigned short* KB4 = Qb + (size_t)QROWS * 32;        // 8*KPAD*4
  unsigned short* VB5 = KB4 + (size_t)8 * KPAD * 4;     // 8*5*KPAD
  unsigned short* W1B = VB5 + (size_t)8 * 5 * KPAD;     // NL*FFD*32
  unsigned short* W2B = W1B + (size_t)NLAYER * FFD * 32;
  float4* AP = (float4*)(((size_t)(W2B + (size_t)NLAYER * FFD * 32) + 15) &
                         ~(size_t)15);                  // NCHUNK*LL*8 float4
  float* LP = (float*)(AP + (size_t)NCHUNK * LL * 8);   // NCHUNK*LL*8 floats
  float* PART2 = (float*)AP;   // aliased; AP dead once oproj has run

  const int NROWB = (LL + 7) / 8;                       // 513

  k_init<<<1024, 256, 0, stream>>>(data, lin_w, lin_b, qkv_w, qkv_b,
                                   ff1_w, ff2_w, X, Qb, KB4, VB5, W1B, W2B);
  for (int l = 0; l < NLAYER; ++l) {
    k_attn<<<dim3(17, 8, NCHUNK), 256, 0, stream>>>(Qb, KB4, VB5, LP, AP);
    k_oproj<<<NROWB, 256, 0, stream>>>(
        LP, (const float*)AP, X, Xb, out_w + (size_t)l * 32 * 32,
        out_b + (size_t)l * 32,
        ln1_g + (size_t)l * 32, ln1_b + (size_t)l * 32);
    k_ffnA<<<dim3((LL + RT - 1) / RT, NSEG), 256, 0, stream>>>(
        Xb, W1B + (size_t)l * FFD * 32, ff1_b + (size_t)l * FFD,
        W2B + (size_t)l * FFD * 32, PART2);
    int nl = l + 1;
    int do_qkv = (nl < NLAYER) ? 1 : 0;
    const float* qw = qkv_w + (size_t)(do_qkv ? nl : 0) * 96 * 32;
    const float* qb = qkv_b + (size_t)(do_qkv ? nl : 0) * 96;
    k_ffnB_qkv<<<NROWB, 256, 0, stream>>>(
        X, PART2, ff2_b + (size_t)l * 32,
        ln2_g + (size_t)l * 32, ln2_b + (size_t)l * 32,
        qw, qb, Qb, KB4, VB5, do_qkv, cls_w, cls_b, (float*)d_out);
  }
}

// Round 12
// 400.622 us; speedup vs baseline: 7.9267x; 1.0922x over previous
//
#include <hip/hip_runtime.h>
#include <hip/hip_bf16.h>
#include <math.h>

// Problem constants
#define SEQ 4096
#define LL  4097           // sequence + CLS
#define HDIM 32
#define FFD 2048
#define NLAYER 6
#define EPSLN 1e-5f
#define NCHUNK 16          // split-K chunks over keys (256 keys each, last 288)
#define KPAD 4128          // keys 0..4096 padded to 129*32
#define QROWS 4352         // 17 blocks * 4 waves * 64 queries
#define RB2 16             // fused FFN kernel row block

#if __has_builtin(__builtin_amdgcn_exp2f)
#define EXP2 __builtin_amdgcn_exp2f
#else
#define EXP2 exp2f
#endif

#define QSCALE 0.7213475204444817f   // 0.5 * log2(e)

typedef short bf16x8 __attribute__((ext_vector_type(8)));
typedef short bf16x4 __attribute__((ext_vector_type(4)));
typedef float f32x4 __attribute__((ext_vector_type(4)));

__device__ __forceinline__ unsigned short f2b(float f) {   // fp32 -> bf16 RNE
  unsigned int b = __float_as_uint(f);
  b += 0x7FFFu + ((b >> 16) & 1u);
  return (unsigned short)(b >> 16);
}

__device__ __forceinline__ unsigned int pk_bf16(float a, float b) {
  __hip_bfloat162 h = __float22bfloat162_rn(make_float2(a, b));
  return *(unsigned int*)&h;
}

// K=16 bf16 MFMA for QK^T (head dim 4 -> half the matrix-pipe cost of K=32).
__device__ __forceinline__ f32x4 mfma_qk(bf16x4 a, bf16x4 b, f32x4 c) {
#if __has_builtin(__builtin_amdgcn_mfma_f32_16x16x16bf16_1k)
  return __builtin_amdgcn_mfma_f32_16x16x16bf16_1k(a, b, c, 0, 0, 0);
#else
  bf16x8 a8 = {a[0], a[1], a[2], a[3], 0, 0, 0, 0};
  bf16x8 b8 = {b[0], b[1], b[2], b[3], 0, 0, 0, 0};
  return __builtin_amdgcn_mfma_f32_16x16x32_bf16(a8, b8, c, 0, 0, 0);
#endif
}

// Buffers:
//  Qb  [QROWS][32]  bf16, pre-scaled by QSCALE (pad rows zero).
//  KB4 [8][KPAD][4] bf16 — head h's 4 K dims per key; pad rows zeroed once.
//  VB5 [8][5][KPAD] bf16, rows 0..3 = V dims (permuted key order), row 4 =
//      validity. Key permutation within 32-blocks: pos = ((w&15)<<1) | (w>>4)
//      — so pk(exp(S[k]), exp(S[k+16])) is directly the PV B-frag in-lane.
//  AP [(c*LL+q)*32 + h*4+d] float — split-K numerator partials; a row's 32
//      lanes read ONE contiguous 128B line per chunk.
//  LP [(c*LL+q)*8 + h] float — split-K denominators, one 32B segment/row.
//  X  [LL][32] fp32 — residual stream (updated at LN2 only).

// wave-level qkv projection + bf16 stores. y = this thread's (row,ch) value.
__device__ __forceinline__ void qkv_wave(float y, int row, bool ok, int lane,
    const float* __restrict__ qw, const float* __restrict__ qb,
    unsigned short* __restrict__ Qb, unsigned short* __restrict__ KB4,
    unsigned short* __restrict__ VB5) {
  int ch = lane & 31;
  float xv[32];
#pragma unroll
  for (int k = 0; k < 32; ++k) xv[k] = __shfl(y, (lane & 32) + k, 64);
#pragma unroll
  for (int t3 = 0; t3 < 3; ++t3) {
    int cc = t3 * 32 + ch;
    const float4* wr = (const float4*)(qw + (size_t)cc * 32);
    float acc = qb[cc];
#pragma unroll
    for (int k8 = 0; k8 < 8; ++k8) {
      float4 wv = wr[k8];
      acc = fmaf(xv[4 * k8 + 0], wv.x, acc);
      acc = fmaf(xv[4 * k8 + 1], wv.y, acc);
      acc = fmaf(xv[4 * k8 + 2], wv.z, acc);
      acc = fmaf(xv[4 * k8 + 3], wv.w, acc);
    }
    if (ok) {
      int h = ch >> 2;
      if (t3 == 0) {
        Qb[(size_t)row * 32 + ch] = f2b(QSCALE * acc);
      } else if (t3 == 1) {
        KB4[((size_t)h * KPAD + row) * 4 + (ch & 3)] = f2b(acc);
      } else {
        int w = row & 31;
        int pos = ((w & 15) << 1) | (w >> 4);
        VB5[((size_t)h * 5 + (ch & 3)) * KPAD + (row & ~31) + pos] = f2b(acc);
      }
    }
  }
}

// ---- init: weight cvt + pad zeroing + embed + layer-0 qkv (all disjoint) ---
__global__ __launch_bounds__(256) void k_init(const float* __restrict__ data,
    const float* __restrict__ lin_w, const float* __restrict__ lin_b,
    const float* __restrict__ qkv_w, const float* __restrict__ qkv_b,
    const float* __restrict__ ff1_w, const float* __restrict__ ff2_w,
    float* __restrict__ X, unsigned short* __restrict__ Qb,
    unsigned short* __restrict__ KB4, unsigned short* __restrict__ VB5,
    unsigned short* __restrict__ W1B, unsigned short* __restrict__ W2B) {
  int gid = blockIdx.x * 256 + threadIdx.x;
  int gsz = gridDim.x * 256;
  const int NW = NLAYER * FFD * 32;
  for (int i = gid; i < NW; i += gsz) {
    W1B[i] = f2b(ff1_w[i]);
    W2B[i] = f2b(ff2_w[i]);
  }
  for (int i = gid; i < (QROWS - LL) * 32; i += gsz)
    Qb[(size_t)LL * 32 + i] = 0;                    // query pad rows
  for (int i = gid; i < 8 * (KPAD - LL) * 4; i += gsz) {
    int hh = i / ((KPAD - LL) * 4);
    int rem = i % ((KPAD - LL) * 4);
    KB4[((size_t)hh * KPAD + LL) * 4 + rem] = 0;    // K pad rows
  }
  for (int i = gid; i < 8 * 5 * KPAD; i += gsz) {
    int col = i % KPAD;
    int dd = (i / KPAD) % 5;
    if (dd == 4) {
      int key = (col & ~31) + ((col & 1) << 4) + ((col & 31) >> 1);
      VB5[i] = (key <= 4096) ? 0x3F80 : 0;          // validity row
    } else if (col > 4096) {
      VB5[i] = 0;                                   // pad-key V entries
    }
  }
  // embed + layer-0 qkv: wave items, 2 rows each
  int wave = threadIdx.x >> 6, lane = threadIdx.x & 63;
  int r = lane >> 5, ch = lane & 31;
  unsigned wgid = blockIdx.x * 4 + wave;
  for (unsigned it = wgid; it < 2049; it += gridDim.x * 4) {
    int row = it * 2 + r;
    bool ok = row < LL;
    float val = 0.f;
    if (ok) {
      if (row == 0) {
        val = -1.0f;
      } else {
        int s = row - 1;
        float ts = data[s * 3 + 0];
        float f0 = data[s * 3 + 1];
        float f1 = data[s * 3 + 2];
        float lin = f0 * lin_w[ch * 2 + 0] + f1 * lin_w[ch * 2 + 1] + lin_b[ch];
        lin = fmaxf(lin, 0.0f);
        int tsi = (int)(ts / 100.0f);
        int j = ch >> 1;
        float aj = (float)(2 * j) * (float)(-0.28782313662425575);
        float divj = (float)exp((double)aj);
        float ang = (float)tsi * divj;
        float pe = (ch & 1) ? cosf(ang) : sinf(ang);
        val = lin + pe;
      }
      X[(size_t)row * HDIM + ch] = val;
    }
    qkv_wave(val, row, ok, lane, qkv_w, qkv_b, Qb, KB4, VB5);
  }
}

// ---- attention, swapped-operand MFMA: NO LDS, no transpose (r11 body) ------
__global__ __launch_bounds__(256, 4) void k_attn(
    const unsigned short* __restrict__ Qb, const unsigned short* __restrict__ KB4,
    const unsigned short* __restrict__ VB5, float* __restrict__ LP,
    float4* __restrict__ AP4) {
  int tid = threadIdx.x;
  int wave = tid >> 6, lane = tid & 63;
  int l16 = lane & 15, quad = lane >> 4;
  int h = blockIdx.y, c = blockIdx.z;
  int qs = blockIdx.x * 4 + wave;
  if (qs >= 65) return;                  // wave-uniform exit, no barriers used
  int q0 = qs * 64;
  int kb0 = c * 256;
  int nkb = (c == NCHUNK - 1) ? 9 : 8;

  const unsigned short* KBh = KB4 + (size_t)h * KPAD * 4;
  const unsigned short* VBh = VB5 + (size_t)h * 5 * KPAD;
  const bool kl = (quad == (h & 3));    // carrying quad for K=16 contraction
  const bool vl = (l16 < 5);            // only V rows 0..4 are nonzero
  const int qcol0 = (h >> 2) * 16 + quad * 4;   // Q columns for this quad

  bf16x4 aq[4];                          // Q tiles: B-operand (row = l16 = q)
#pragma unroll
  for (int t = 0; t < 4; ++t)
    aq[t] = *(const bf16x4*)&Qb[(size_t)(q0 + t * 16 + l16) * 32 + qcol0];

  const bf16x4 zb4 = {0, 0, 0, 0};
  const bf16x8 zb8 = {0, 0, 0, 0, 0, 0, 0, 0};
  f32x4 acc0[4], acc1[4];
#pragma unroll
  for (int t = 0; t < 4; ++t) {
    acc0[t] = (f32x4){0.f, 0.f, 0.f, 0.f};
    acc1[t] = (f32x4){0.f, 0.f, 0.f, 0.f};
  }

  auto step = [&](int k0, f32x4* acc) {
    bf16x4 bk0 = kl ? *(const bf16x4*)&KBh[(size_t)(k0 + l16) * 4] : zb4;
    bf16x4 bk1 = kl ? *(const bf16x4*)&KBh[(size_t)(k0 + 16 + l16) * 4] : zb4;
    bf16x8 bv = vl ? *(const bf16x8*)&VBh[(size_t)l16 * KPAD + k0 + quad * 8]
                   : zb8;
    f32x4 z = {0.f, 0.f, 0.f, 0.f};
    unsigned pf[4][4];                   // packed P fragments (bf16x8 each)
#pragma unroll
    for (int t = 0; t < 4; ++t) {
      f32x4 s0 = mfma_qk(bk0, aq[t], z);
      f32x4 s1 = mfma_qk(bk1, aq[t], z);
#pragma unroll
      for (int reg = 0; reg < 4; ++reg)
        pf[t][reg] = pk_bf16(EXP2(s0[reg]), EXP2(s1[reg]));
    }
#pragma unroll
    for (int t = 0; t < 4; ++t) {
      bf16x8 pb = *(const bf16x8*)&pf[t][0];
      acc[t] = __builtin_amdgcn_mfma_f32_16x16x32_bf16(bv, pb, acc[t], 0, 0, 0);
    }
  };

  int kb = 0;
  for (; kb + 2 <= nkb; kb += 2) {
    step(kb0 + kb * 32, acc0);
    step(kb0 + (kb + 1) * 32, acc1);
  }
  if (kb < nkb) step(kb0 + kb * 32, acc0);

  // Output: lane holds O^T rows d=quad*4+reg for q=l16 of each tile.
#pragma unroll
  for (int t = 0; t < 4; ++t) {
    f32x4 a = acc0[t] + acc1[t];
    int q = q0 + t * 16 + l16;
    if (q < LL) {
      if (quad == 0) {
        AP4[((size_t)c * LL + q) * 8 + h] = make_float4(a[0], a[1], a[2], a[3]);
      } else if (quad == 1) {
        LP[((size_t)c * LL + q) * 8 + h] = a[0];
      }
    }
  }
}

// ---- fused per-16-row block: oproj+LN1 -> full FFN -> LN2 -> qkv/cls -------
// grid (257) x 512 threads (8 waves). Wave w owns the 256-wide f-slice
// [w*256, w*256+256). No redundant work: partials read once, weights
// L2-resident, per-wave GEMM work identical to the split ffnA wave.
// 2 blocks/CU resident (VGPR<=128, LDS ~55KB) -> full grid concurrent.
__global__ __launch_bounds__(512, 4) void k_ffnF(const float* __restrict__ LP,
    const float* __restrict__ APf, float* __restrict__ X,
    const float* __restrict__ ow, const float* __restrict__ ob,
    const float* __restrict__ g1, const float* __restrict__ b1ln,
    const unsigned short* __restrict__ w1b, const float* __restrict__ fb1,
    const unsigned short* __restrict__ w2b, const float* __restrict__ fb2,
    const float* __restrict__ g2, const float* __restrict__ b2ln,
    const float* __restrict__ qw, const float* __restrict__ qb,
    unsigned short* __restrict__ Qb, unsigned short* __restrict__ KB4,
    unsigned short* __restrict__ VB5, int do_qkv,
    const float* __restrict__ cw, const float* __restrict__ cb,
    float* __restrict__ out) {
  __shared__ unsigned short Xa[RB2][32];      // bf16 LN1 out (GEMM1 A-tile)
  __shared__ float Y1[RB2][32];               // fp32 LN1 out (FFN residual)
  __shared__ unsigned short Fsb[8][16 * 136]; // per-wave transpose buffers
  __shared__ float Pr[8][RB2 * 33];           // per-wave GEMM2 partials
  int tid = threadIdx.x;
  int wave = tid >> 6, lane = tid & 63;
  int l16 = lane & 15, quad = lane >> 4;
  int r = lane >> 5, ch = lane & 31;
  int r0 = blockIdx.x * RB2;

  // Phase A: split-K combine + o-proj + residual + LN1 (2 rows per wave)
  {
    int rl = wave * 2 + r;
    int row = r0 + rl;
    bool ok = row < LL;
    int hh = ch >> 2;
    float L = 0.f, A = 0.f;
    if (ok) {
#pragma unroll
      for (int c = 0; c < NCHUNK; ++c) {
        A += APf[((size_t)c * LL + row) * 32 + ch];
        L += LP[((size_t)c * LL + row) * 8 + hh];
      }
    }
    float os = ok ? A / L : 0.f;
    float acc = 0.f;
    const float4* owr = (const float4*)(ow + (size_t)ch * 32);
#pragma unroll
    for (int k8 = 0; k8 < 8; ++k8) {
      float4 wv = owr[k8];
      acc = fmaf(__shfl(os, (lane & 32) + 4 * k8 + 0, 64), wv.x, acc);
      acc = fmaf(__shfl(os, (lane & 32) + 4 * k8 + 1, 64), wv.y, acc);
      acc = fmaf(__shfl(os, (lane & 32) + 4 * k8 + 2, 64), wv.z, acc);
      acc = fmaf(__shfl(os, (lane & 32) + 4 * k8 + 3, 64), wv.w, acc);
    }
    float val = ok ? (X[(size_t)row * HDIM + ch] + acc + ob[ch]) : 0.f;
    float mean = val;
#pragma unroll
    for (int off = 16; off > 0; off >>= 1) mean += __shfl_xor(mean, off, 32);
    mean *= (1.f / 32.f);
    float d2 = val - mean;
    float var = d2 * d2;
#pragma unroll
    for (int off = 16; off > 0; off >>= 1) var += __shfl_xor(var, off, 32);
    var *= (1.f / 32.f);
    float y = d2 / sqrtf(var + EPSLN) * g1[ch] + b1ln[ch];
    Y1[rl][ch] = y;
    Xa[rl][ch] = ok ? f2b(y) : 0;
  }
  __syncthreads();

  // Phase B: FFN over this wave's 256-wide f-slice (wave-private transpose)
  bf16x8 a1 = *(const bf16x8*)&Xa[l16][quad * 8];
  f32x4 acc2[2] = {{0.f, 0.f, 0.f, 0.f}, {0.f, 0.f, 0.f, 0.f}};
  int fs0 = wave * 256;
#pragma unroll
  for (int sg = 0; sg < 2; ++sg) {
    int f0 = fs0 + sg * 128;
    f32x4 c1[8];
#pragma unroll
    for (int t = 0; t < 8; ++t) {
      bf16x8 b =
          *(const bf16x8*)&w1b[(size_t)(f0 + t * 16 + l16) * 32 + quad * 8];
      f32x4 z = {0.f, 0.f, 0.f, 0.f};
      c1[t] = __builtin_amdgcn_mfma_f32_16x16x32_bf16(a1, b, z, 0, 0, 0);
    }
#pragma unroll
    for (int t = 0; t < 8; ++t) {
      float bb = fb1[f0 + t * 16 + l16];
#pragma unroll
      for (int reg = 0; reg < 4; ++reg) {
        float v = fmaxf(c1[t][reg] + bb, 0.f);
        Fsb[wave][(quad * 4 + reg) * 136 + t * 16 + l16] = f2b(v);
      }
    }
    // Fsb is wave-private; in-order per-wave DS -> no barrier
#pragma unroll
    for (int kt = 0; kt < 4; ++kt) {
      bf16x8 a2 = *(const bf16x8*)&Fsb[wave][l16 * 136 + kt * 32 + quad * 8];
#pragma unroll
      for (int u = 0; u < 2; ++u) {
        bf16x8 b = *(const bf16x8*)&w2b[(size_t)(u * 16 + l16) * FFD + f0 +
                                        kt * 32 + quad * 8];
        acc2[u] =
            __builtin_amdgcn_mfma_f32_16x16x32_bf16(a2, b, acc2[u], 0, 0, 0);
      }
    }
  }
#pragma unroll
  for (int u = 0; u < 2; ++u)
#pragma unroll
    for (int reg = 0; reg < 4; ++reg)
      Pr[wave][(quad * 4 + reg) * 33 + u * 16 + l16] = acc2[u][reg];
  __syncthreads();

  // Phase C: reduce 8 wave partials + residual + LN2 + next qkv / classifier
  {
    int rl = wave * 2 + r;
    int row = r0 + rl;
    bool ok = row < LL;
    float s = 0.f;
#pragma unroll
    for (int w = 0; w < 8; ++w) s += Pr[w][rl * 33 + ch];
    float val = ok ? (Y1[rl][ch] + s + fb2[ch]) : 0.f;
    float mean = val;
#pragma unroll
    for (int off = 16; off > 0; off >>= 1) mean += __shfl_xor(mean, off, 32);
    mean *= (1.f / 32.f);
    float d2 = val - mean;
    float var = d2 * d2;
#pragma unroll
    for (int off = 16; off > 0; off >>= 1) var += __shfl_xor(var, off, 32);
    var *= (1.f / 32.f);
    float y = d2 / sqrtf(var + EPSLN) * g2[ch] + b2ln[ch];
    if (ok) X[(size_t)row * HDIM + ch] = y;
    if (do_qkv) {
      qkv_wave(y, row, ok, lane, qw, qb, Qb, KB4, VB5);
    } else if (blockIdx.x == 0 && wave == 0 && r == 0) {
      // row 0 = CLS
      float t = y * cw[ch];
#pragma unroll
      for (int off = 16; off > 0; off >>= 1) t += __shfl_xor(t, off, 32);
      if (ch == 0) out[0] = 1.f / (1.f + expf(-(t + cb[0])));
    }
  }
}

extern "C" void kernel_launch(void* const* d_in, const int* in_sizes, int n_in,
                              void* d_out, int out_size, void* d_ws,
                              size_t ws_size, hipStream_t stream) {
  const float* data  = (const float*)d_in[0];
  const float* lin_w = (const float*)d_in[1];
  const float* lin_b = (const float*)d_in[2];
  const float* qkv_w = (const float*)d_in[3];
  const float* qkv_b = (const float*)d_in[4];
  const float* out_w = (const float*)d_in[5];
  const float* out_b = (const float*)d_in[6];
  const float* ln1_g = (const float*)d_in[7];
  const float* ln1_b = (const float*)d_in[8];
  const float* ff1_w = (const float*)d_in[9];
  const float* ff1_b = (const float*)d_in[10];
  const float* ff2_w = (const float*)d_in[11];
  const float* ff2_b = (const float*)d_in[12];
  const float* ln2_g = (const float*)d_in[13];
  const float* ln2_b = (const float*)d_in[14];
  const float* cls_w = (const float*)d_in[15];
  const float* cls_b = (const float*)d_in[16];

  char* wsb = (char*)d_ws;
  float* X = (float*)wsb;                               // LL*32 fp32
  unsigned short* Qb  = (unsigned short*)(X + (size_t)LL * 32);
  unsigned short* KB4 = Qb + (size_t)QROWS * 32;        // 8*KPAD*4
  unsigned short* VB5 = KB4 + (size_t)8 * KPAD * 4;     // 8*5*KPAD
  unsigned short* W1B = VB5 + (size_t)8 * 5 * KPAD;     // NL*FFD*32
  unsigned short* W2B = W1B + (size_t)NLAYER * FFD * 32;
  float4* AP = (float4*)(((size_t)(W2B + (size_t)NLAYER * FFD * 32) + 15) &
                         ~(size_t)15);                  // NCHUNK*LL*8 float4
  float* LP = (float*)(AP + (size_t)NCHUNK * LL * 8);   // NCHUNK*LL*8 floats

  k_init<<<1024, 256, 0, stream>>>(data, lin_w, lin_b, qkv_w, qkv_b,
                                   ff1_w, ff2_w, X, Qb, KB4, VB5, W1B, W2B);
  for (int l = 0; l < NLAYER; ++l) {
    k_attn<<<dim3(17, 8, NCHUNK), 256, 0, stream>>>(Qb, KB4, VB5, LP, AP);
    int nl = l + 1;
    int do_qkv = (nl < NLAYER) ? 1 : 0;
    const float* qw = qkv_w + (size_t)(do_qkv ? nl : 0) * 96 * 32;
    const float* qb = qkv_b + (size_t)(do_qkv ? nl : 0) * 96;
    k_ffnF<<<(LL + RB2 - 1) / RB2, 512, 0, stream>>>(
        LP, (const float*)AP, X,
        out_w + (size_t)l * 32 * 32, out_b + (size_t)l * 32,
        ln1_g + (size_t)l * 32, ln1_b + (size_t)l * 32,
        W1B + (size_t)l * FFD * 32, ff1_b + (size_t)l * FFD,
        W2B + (size_t)l * FFD * 32, ff2_b + (size_t)l * 32,
        ln2_g + (size_t)l * 32, ln2_b + (size_t)l * 32,
        qw, qb, Qb, KB4, VB5, do_qkv, cls_w, cls_b, (float*)d_out);
  }
}